// Round 1
// baseline (489.420 us; speedup 1.0000x reference)
//
#include <hip/hip_runtime.h>
#include <hip/hip_bf16.h>

// Problem constants
#define B_   16
#define C_   512
#define HW_  2304
#define NH_  8
#define HD_  64
#define SCALE_ 0.125f

typedef __bf16 bf16x8 __attribute__((ext_vector_type(8)));
typedef __bf16 bf16x4 __attribute__((ext_vector_type(4)));
typedef __bf16 bf16x2 __attribute__((ext_vector_type(2)));
typedef float  f32x4  __attribute__((ext_vector_type(4)));

#define MFMA16(a, b, c) __builtin_amdgcn_mfma_f32_16x16x32_bf16((a), (b), (c), 0, 0, 0)

// ---------------------------------------------------------------------------
// Kernel 1: QKV projections.  Y_p[b, o, hw] = sum_c W_p[o,c] * X_p[b,c,hw] + bias_p[o]
// 128x128 tile, BK=32, 256 threads (4 waves, each 64x64).
// A (weights, fp32, k-contiguous) -> As[128][40]  (pad 8, rows 80B: 16B aligned)
// B (features, fp32, n-contiguous) -> packed-pair transpose: element (n,kk) at
//   Bs[(n>>1)*72 + (n&1)*32 + kk]  -- all stores are aligned b128, banks spread.
// ---------------------------------------------------------------------------
__global__ __launch_bounds__(256) void proj_qkv(
    const float* __restrict__ qf, const float* __restrict__ kf, const float* __restrict__ vf,
    const float* __restrict__ Wq, const float* __restrict__ Wk, const float* __restrict__ Wv,
    const float* __restrict__ bq, const float* __restrict__ bk, const float* __restrict__ bv,
    __bf16* __restrict__ ws)
{
    const int z = blockIdx.z;
    const int p = z >> 4;          // 0=Q,1=K,2=V
    const int b = z & 15;
    const float* X;
    const float* W;
    const float* bias;
    if (p == 0)      { X = qf; W = Wq; bias = bq; }
    else if (p == 1) { X = kf; W = Wk; bias = bk; }
    else             { X = vf; W = Wv; bias = bv; }
    __bf16* Y = ws + (size_t)p * ((size_t)B_ * C_ * HW_)
                   + (size_t)b * C_ * HW_;
    X += (size_t)b * C_ * HW_;

    const int n0 = blockIdx.x * 128;   // hw
    const int m0 = blockIdx.y * 128;   // out channel

    __shared__ __align__(16) __bf16 As[128 * 40];
    __shared__ __align__(16) __bf16 Bs[64 * 72];

    const int t    = threadIdx.x;
    const int w    = t >> 6;
    const int lane = t & 63;
    const int l16  = lane & 15;
    const int q    = lane >> 4;
    const int wm   = w >> 1;
    const int wn   = w & 1;

    // staging assignments
    const int mA = t >> 1;            // 0..127
    const int kA = (t & 1) * 16;      // 0/16
    const int mB = t & 63;            // n-pair index 0..63
    const int kB = (t >> 6) * 8;      // 0,8,16,24

    f32x4 acc[4][4] = {};

    for (int ks = 0; ks < 16; ++ks) {
        const int k0 = ks * 32;
        __syncthreads();
        // ---- stage A tile (weights) ----
        {
            const float* src = W + (size_t)(m0 + mA) * 512 + k0 + kA;
            const float4 f0 = *(const float4*)(src + 0);
            const float4 f1 = *(const float4*)(src + 4);
            const float4 f2 = *(const float4*)(src + 8);
            const float4 f3 = *(const float4*)(src + 12);
            bf16x8 v0, v1;
            v0[0] = (__bf16)f0.x; v0[1] = (__bf16)f0.y; v0[2] = (__bf16)f0.z; v0[3] = (__bf16)f0.w;
            v0[4] = (__bf16)f1.x; v0[5] = (__bf16)f1.y; v0[6] = (__bf16)f1.z; v0[7] = (__bf16)f1.w;
            v1[0] = (__bf16)f2.x; v1[1] = (__bf16)f2.y; v1[2] = (__bf16)f2.z; v1[3] = (__bf16)f2.w;
            v1[4] = (__bf16)f3.x; v1[5] = (__bf16)f3.y; v1[6] = (__bf16)f3.z; v1[7] = (__bf16)f3.w;
            *(bf16x8*)&As[mA * 40 + kA]     = v0;
            *(bf16x8*)&As[mA * 40 + kA + 8] = v1;
        }
        // ---- stage B tile (features, transpose to (n,k)) ----
        {
            bf16x8 r0, r1;
            #pragma unroll
            for (int j = 0; j < 8; ++j) {
                const float2 v = *(const float2*)&X[(size_t)(k0 + kB + j) * HW_ + n0 + 2 * mB];
                r0[j] = (__bf16)v.x;
                r1[j] = (__bf16)v.y;
            }
            *(bf16x8*)&Bs[mB * 72 + kB]      = r0;
            *(bf16x8*)&Bs[mB * 72 + 32 + kB] = r1;
        }
        __syncthreads();
        // ---- MFMA ----
        bf16x8 af[4], bfr[4];
        #pragma unroll
        for (int mi = 0; mi < 4; ++mi)
            af[mi] = *(bf16x8*)&As[(wm * 64 + mi * 16 + l16) * 40 + q * 8];
        #pragma unroll
        for (int ni = 0; ni < 4; ++ni) {
            const int n = wn * 64 + ni * 16 + l16;
            bfr[ni] = *(bf16x8*)&Bs[(n >> 1) * 72 + (n & 1) * 32 + q * 8];
        }
        #pragma unroll
        for (int mi = 0; mi < 4; ++mi)
            #pragma unroll
            for (int ni = 0; ni < 4; ++ni)
                acc[mi][ni] = MFMA16(af[mi], bfr[ni], acc[mi][ni]);
    }

    // ---- epilogue: bias + bf16 store ----
    #pragma unroll
    for (int mi = 0; mi < 4; ++mi) {
        #pragma unroll
        for (int r = 0; r < 4; ++r) {
            const int m = m0 + wm * 64 + mi * 16 + q * 4 + r;
            const float bv_ = bias[m];
            #pragma unroll
            for (int ni = 0; ni < 4; ++ni) {
                const int n = n0 + wn * 64 + ni * 16 + l16;
                Y[(size_t)m * HW_ + n] = (__bf16)(acc[mi][ni][r] + bv_);
            }
        }
    }
}

// ---------------------------------------------------------------------------
// Kernel 2a: scores + softmax per (b, head).  S[h,k] = sum_d Q[h,d]K[k,d] * SCALE
// M=N=64, K=2304, BK=64. 4 waves, wave w owns rows w*16..+16 (all 64 cols).
// Softmax in-register via __shfl_xor over the 16 lanes of each quad.
// Writes P (bf16, [bn][64][64]).
// ---------------------------------------------------------------------------
__global__ __launch_bounds__(256) void attn_scores(
    const __bf16* __restrict__ Qw, const __bf16* __restrict__ Kw, __bf16* __restrict__ Pw)
{
    const int bn = blockIdx.x;               // b*8 + head
    const __bf16* Qb = Qw + (size_t)bn * 64 * HW_;
    const __bf16* Kb = Kw + (size_t)bn * 64 * HW_;

    __shared__ __align__(16) __bf16 Qs[64 * 72];
    __shared__ __align__(16) __bf16 Ks[64 * 72];

    const int t    = threadIdx.x;
    const int w    = t >> 6;
    const int lane = t & 63;
    const int l16  = lane & 15;
    const int q    = lane >> 4;
    const int row  = t >> 2;            // 0..63
    const int kc   = (t & 3) * 16;      // 0,16,32,48

    f32x4 acc[4] = {};

    for (int it = 0; it < 36; ++it) {
        const int k0 = it * 64;
        __syncthreads();
        *(bf16x8*)&Qs[row * 72 + kc]     = *(const bf16x8*)&Qb[(size_t)row * HW_ + k0 + kc];
        *(bf16x8*)&Qs[row * 72 + kc + 8] = *(const bf16x8*)&Qb[(size_t)row * HW_ + k0 + kc + 8];
        *(bf16x8*)&Ks[row * 72 + kc]     = *(const bf16x8*)&Kb[(size_t)row * HW_ + k0 + kc];
        *(bf16x8*)&Ks[row * 72 + kc + 8] = *(const bf16x8*)&Kb[(size_t)row * HW_ + k0 + kc + 8];
        __syncthreads();
        #pragma unroll
        for (int kk = 0; kk < 2; ++kk) {
            const bf16x8 a = *(bf16x8*)&Qs[(w * 16 + l16) * 72 + kk * 32 + q * 8];
            #pragma unroll
            for (int ni = 0; ni < 4; ++ni) {
                const bf16x8 bb = *(bf16x8*)&Ks[(ni * 16 + l16) * 72 + kk * 32 + q * 8];
                acc[ni] = MFMA16(a, bb, acc[ni]);
            }
        }
    }

    // scale
    #pragma unroll
    for (int ni = 0; ni < 4; ++ni)
        #pragma unroll
        for (int r = 0; r < 4; ++r)
            acc[ni][r] *= SCALE_;

    // softmax over cols (64 values per row: 4 regs x 16 lanes of the quad)
    #pragma unroll
    for (int r = 0; r < 4; ++r) {
        float mx = fmaxf(fmaxf(acc[0][r], acc[1][r]), fmaxf(acc[2][r], acc[3][r]));
        mx = fmaxf(mx, __shfl_xor(mx, 1));
        mx = fmaxf(mx, __shfl_xor(mx, 2));
        mx = fmaxf(mx, __shfl_xor(mx, 4));
        mx = fmaxf(mx, __shfl_xor(mx, 8));
        float s = 0.f;
        #pragma unroll
        for (int ni = 0; ni < 4; ++ni) {
            const float e = expf(acc[ni][r] - mx);
            acc[ni][r] = e;
            s += e;
        }
        s += __shfl_xor(s, 1);
        s += __shfl_xor(s, 2);
        s += __shfl_xor(s, 4);
        s += __shfl_xor(s, 8);
        const float inv = 1.f / s;
        #pragma unroll
        for (int ni = 0; ni < 4; ++ni)
            acc[ni][r] *= inv;
    }

    // write P
    #pragma unroll
    for (int r = 0; r < 4; ++r)
        #pragma unroll
        for (int ni = 0; ni < 4; ++ni)
            Pw[(size_t)bn * 4096 + (w * 16 + q * 4 + r) * 64 + ni * 16 + l16] =
                (__bf16)acc[ni][r];
}

// ---------------------------------------------------------------------------
// Kernel 2b: O = P @ V per (b, head, d-slab).  Grid (9, 128). Each wave handles
// 64 d-columns: loads its V chunk into a quad-packed transposed LDS tile
// (element (dlocal,k) at Vt[(dl>>2)*264 + (dl&3)*64 + k], aligned b128 stores),
// P comes from LDS in A-operand layout. 32 MFMAs per wave. Writes AO bf16.
// ---------------------------------------------------------------------------
__global__ __launch_bounds__(256) void attn_pv(
    const __bf16* __restrict__ Pw, const __bf16* __restrict__ Vw, __bf16* __restrict__ AO)
{
    const int dsl = blockIdx.x;     // 0..8
    const int bn  = blockIdx.y;     // 0..127
    const int t    = threadIdx.x;
    const int w    = t >> 6;
    const int lane = t & 63;
    const int l16  = lane & 15;
    const int q    = lane >> 4;

    __shared__ __align__(16) __bf16 Ps[64 * 72];
    __shared__ __align__(16) __bf16 Vt[4][16 * 264];

    // load P -> LDS
    {
        const int row = t >> 2;
        const int kc  = (t & 3) * 16;
        *(bf16x8*)&Ps[row * 72 + kc]     = *(const bf16x8*)&Pw[(size_t)bn * 4096 + row * 64 + kc];
        *(bf16x8*)&Ps[row * 72 + kc + 8] = *(const bf16x8*)&Pw[(size_t)bn * 4096 + row * 64 + kc + 8];
    }

    // load V chunk (wave-private region, transposed)
    const __bf16* Vb = Vw + (size_t)bn * 64 * HW_;
    const int d0w = dsl * 256 + w * 64;
    {
        const int m4 = lane & 15;            // d-quad index
        const int kh = (lane >> 4) * 16;     // k base
        __bf16 rr[4][16];
        #pragma unroll
        for (int j = 0; j < 16; ++j) {
            const bf16x4 v = *(const bf16x4*)&Vb[(size_t)(kh + j) * HW_ + d0w + 4 * m4];
            #pragma unroll
            for (int e = 0; e < 4; ++e) rr[e][j] = v[e];
        }
        #pragma unroll
        for (int e = 0; e < 4; ++e) {
            bf16x8 s0, s1;
            #pragma unroll
            for (int j = 0; j < 8; ++j) { s0[j] = rr[e][j]; s1[j] = rr[e][8 + j]; }
            *(bf16x8*)&Vt[w][m4 * 264 + e * 64 + kh]     = s0;
            *(bf16x8*)&Vt[w][m4 * 264 + e * 64 + kh + 8] = s1;
        }
    }
    __syncthreads();

    f32x4 acc[4][4] = {};
    #pragma unroll
    for (int kk = 0; kk < 2; ++kk) {
        bf16x8 af[4], bfr[4];
        #pragma unroll
        for (int mi = 0; mi < 4; ++mi)
            af[mi] = *(bf16x8*)&Ps[(mi * 16 + l16) * 72 + kk * 32 + q * 8];
        #pragma unroll
        for (int ni = 0; ni < 4; ++ni) {
            const int dl = ni * 16 + l16;
            bfr[ni] = *(bf16x8*)&Vt[w][(dl >> 2) * 264 + (dl & 3) * 64 + kk * 32 + q * 8];
        }
        #pragma unroll
        for (int mi = 0; mi < 4; ++mi)
            #pragma unroll
            for (int ni = 0; ni < 4; ++ni)
                acc[mi][ni] = MFMA16(af[mi], bfr[ni], acc[mi][ni]);
    }

    #pragma unroll
    for (int mi = 0; mi < 4; ++mi)
        #pragma unroll
        for (int r = 0; r < 4; ++r) {
            const int m = mi * 16 + q * 4 + r;
            #pragma unroll
            for (int ni = 0; ni < 4; ++ni) {
                const int d = d0w + ni * 16 + l16;
                AO[((size_t)bn * 64 + m) * HW_ + d] = (__bf16)acc[mi][ni][r];
            }
        }
}

// ---------------------------------------------------------------------------
// Kernel 3: output projection.  out[b,o,hw] = sum_c Wo[o,c]*AO[b,c,hw] + bo[o]
// Same structure as proj_qkv, B source already bf16, output fp32.
// ---------------------------------------------------------------------------
__global__ __launch_bounds__(256) void proj_out(
    const __bf16* __restrict__ AO, const float* __restrict__ Wo, const float* __restrict__ bo,
    float* __restrict__ out)
{
    const int b  = blockIdx.z;
    const int n0 = blockIdx.x * 128;
    const int m0 = blockIdx.y * 128;
    const __bf16* Xb = AO + (size_t)b * C_ * HW_;
    float* Yb = out + (size_t)b * C_ * HW_;

    __shared__ __align__(16) __bf16 As[128 * 40];
    __shared__ __align__(16) __bf16 Bs[64 * 72];

    const int t    = threadIdx.x;
    const int w    = t >> 6;
    const int lane = t & 63;
    const int l16  = lane & 15;
    const int q    = lane >> 4;
    const int wm   = w >> 1;
    const int wn   = w & 1;

    const int mA = t >> 1;
    const int kA = (t & 1) * 16;
    const int mB = t & 63;
    const int kB = (t >> 6) * 8;

    f32x4 acc[4][4] = {};

    for (int ks = 0; ks < 16; ++ks) {
        const int k0 = ks * 32;
        __syncthreads();
        {
            const float* src = Wo + (size_t)(m0 + mA) * 512 + k0 + kA;
            const float4 f0 = *(const float4*)(src + 0);
            const float4 f1 = *(const float4*)(src + 4);
            const float4 f2 = *(const float4*)(src + 8);
            const float4 f3 = *(const float4*)(src + 12);
            bf16x8 v0, v1;
            v0[0] = (__bf16)f0.x; v0[1] = (__bf16)f0.y; v0[2] = (__bf16)f0.z; v0[3] = (__bf16)f0.w;
            v0[4] = (__bf16)f1.x; v0[5] = (__bf16)f1.y; v0[6] = (__bf16)f1.z; v0[7] = (__bf16)f1.w;
            v1[0] = (__bf16)f2.x; v1[1] = (__bf16)f2.y; v1[2] = (__bf16)f2.z; v1[3] = (__bf16)f2.w;
            v1[4] = (__bf16)f3.x; v1[5] = (__bf16)f3.y; v1[6] = (__bf16)f3.z; v1[7] = (__bf16)f3.w;
            *(bf16x8*)&As[mA * 40 + kA]     = v0;
            *(bf16x8*)&As[mA * 40 + kA + 8] = v1;
        }
        {
            bf16x8 r0, r1;
            #pragma unroll
            for (int j = 0; j < 8; ++j) {
                const bf16x2 v = *(const bf16x2*)&Xb[(size_t)(k0 + kB + j) * HW_ + n0 + 2 * mB];
                r0[j] = v[0];
                r1[j] = v[1];
            }
            *(bf16x8*)&Bs[mB * 72 + kB]      = r0;
            *(bf16x8*)&Bs[mB * 72 + 32 + kB] = r1;
        }
        __syncthreads();
        bf16x8 af[4], bfr[4];
        #pragma unroll
        for (int mi = 0; mi < 4; ++mi)
            af[mi] = *(bf16x8*)&As[(wm * 64 + mi * 16 + l16) * 40 + q * 8];
        #pragma unroll
        for (int ni = 0; ni < 4; ++ni) {
            const int n = wn * 64 + ni * 16 + l16;
            bfr[ni] = *(bf16x8*)&Bs[(n >> 1) * 72 + (n & 1) * 32 + q * 8];
        }
        #pragma unroll
        for (int mi = 0; mi < 4; ++mi)
            #pragma unroll
            for (int ni = 0; ni < 4; ++ni)
                acc[mi][ni] = MFMA16(af[mi], bfr[ni], acc[mi][ni]);
    }

    #pragma unroll
    for (int mi = 0; mi < 4; ++mi) {
        #pragma unroll
        for (int r = 0; r < 4; ++r) {
            const int m = m0 + wm * 64 + mi * 16 + q * 4 + r;
            const float bias = bo[m];
            #pragma unroll
            for (int ni = 0; ni < 4; ++ni) {
                const int n = n0 + wn * 64 + ni * 16 + l16;
                Yb[(size_t)m * HW_ + n] = acc[mi][ni][r] + bias;
            }
        }
    }
}

// ---------------------------------------------------------------------------
extern "C" void kernel_launch(void* const* d_in, const int* in_sizes, int n_in,
                              void* d_out, int out_size, void* d_ws, size_t ws_size,
                              hipStream_t stream)
{
    (void)in_sizes; (void)n_in; (void)out_size; (void)ws_size;
    const float* qf = (const float*)d_in[0];
    const float* kf = (const float*)d_in[1];
    const float* vf = (const float*)d_in[2];
    const float* Wq = (const float*)d_in[3];
    const float* bq = (const float*)d_in[4];
    const float* Wk = (const float*)d_in[5];
    const float* bk = (const float*)d_in[6];
    const float* Wv = (const float*)d_in[7];
    const float* bv = (const float*)d_in[8];
    const float* Wo = (const float*)d_in[9];
    const float* bo = (const float*)d_in[10];

    const size_t QE = (size_t)B_ * C_ * HW_;   // 18,874,368 elems
    __bf16* Qw = (__bf16*)d_ws;
    __bf16* Kw = Qw + QE;
    __bf16* Vw = Qw + 2 * QE;
    __bf16* AO = Qw + 3 * QE;
    __bf16* Pw = Qw + 4 * QE;                  // 128*64*64 bf16 = 1 MB

    proj_qkv   <<<dim3(18, 4, 48), 256, 0, stream>>>(qf, kf, vf, Wq, Wk, Wv, bq, bk, bv, Qw);
    attn_scores<<<dim3(128),       256, 0, stream>>>(Qw, Kw, Pw);
    attn_pv    <<<dim3(9, 128),    256, 0, stream>>>(Pw, Vw, AO);
    proj_out   <<<dim3(18, 4, 16), 256, 0, stream>>>(AO, Wo, bo, (float*)d_out);
}

// Round 2
// 488.409 us; speedup vs baseline: 1.0021x; 1.0021x over previous
//
#include <hip/hip_runtime.h>
#include <hip/hip_bf16.h>

// Problem constants
#define B_   16
#define C_   512
#define HW_  2304
#define NH_  8
#define HD_  64
#define SCALE_ 0.125f

typedef __bf16 bf16x8 __attribute__((ext_vector_type(8)));
typedef __bf16 bf16x4 __attribute__((ext_vector_type(4)));
typedef float  f32x4  __attribute__((ext_vector_type(4)));

#define MFMA16(a, b, c) __builtin_amdgcn_mfma_f32_16x16x32_bf16((a), (b), (c), 0, 0, 0)

// async global->LDS, 16B per lane; lds base must be wave-uniform, lane i lands
// at base + i*16 (guide §5: wave-uniform base + lane*size)
__device__ __forceinline__ void gload_lds16(const void* g, void* l) {
    __builtin_amdgcn_global_load_lds(
        (const __attribute__((address_space(1))) unsigned int*)g,
        (__attribute__((address_space(3))) unsigned int*)l, 16, 0, 0);
}

// ---------------------------------------------------------------------------
// Transpose + convert: X[b][c][hw] fp32 -> XT[b][hw][c] bf16.
// Tile 64c x 128hw. LDS fp32 stride 129 (odd => b32 accesses <=4-way banked).
// ---------------------------------------------------------------------------
__global__ __launch_bounds__(256) void transpose_cvt(
    const float* __restrict__ X, __bf16* __restrict__ XT)
{
    const int b  = blockIdx.z;
    const int c0 = blockIdx.y * 64;
    const int h0 = blockIdx.x * 128;
    const float* Xb = X + (size_t)b * C_ * HW_;
    __bf16* XTb = XT + (size_t)b * HW_ * C_;

    __shared__ float Ts[64 * 129];
    const int t = threadIdx.x;

    #pragma unroll
    for (int p = 0; p < 8; ++p) {
        const int c  = p * 8 + (t >> 5);
        const int hg = (t & 31) * 4;
        const float4 v = *(const float4*)&Xb[(size_t)(c0 + c) * HW_ + h0 + hg];
        Ts[c * 129 + hg + 0] = v.x;
        Ts[c * 129 + hg + 1] = v.y;
        Ts[c * 129 + hg + 2] = v.z;
        Ts[c * 129 + hg + 3] = v.w;
    }
    __syncthreads();
    #pragma unroll
    for (int p = 0; p < 4; ++p) {
        const int hw = p * 32 + (t >> 3);
        const int g  = (t & 7) * 8;
        bf16x8 o;
        #pragma unroll
        for (int e = 0; e < 8; ++e)
            o[e] = (__bf16)Ts[(g + e) * 129 + hw];
        *(bf16x8*)&XTb[(size_t)(h0 + hw) * C_ + c0 + g] = o;
    }
}

// ---------------------------------------------------------------------------
// Projection GEMM (m97 structure): Y[b][o][hw] = sum_c W[o][c] * XT[b][hw][c].
// 128x128 tile, BK=64. A (W fp32) staged via VGPR+cvt; B (XT bf16) staged via
// global_load_lds dwordx4 (rows contiguous, unpadded LDS per the caveat).
// Output bf16 [c][hw] (+bias).
// ---------------------------------------------------------------------------
__global__ __launch_bounds__(256) void proj_gemm(
    const __bf16* __restrict__ XT, const float* __restrict__ W,
    const float* __restrict__ bias, __bf16* __restrict__ Y)
{
    const int b  = blockIdx.z;
    const int n0 = blockIdx.x * 128;   // hw
    const int m0 = blockIdx.y * 128;   // out channel
    const __bf16* XTb = XT + (size_t)b * HW_ * C_;
    __bf16* Yb = Y + (size_t)b * C_ * HW_;

    __shared__ __align__(16) __bf16 As[128 * 64];
    __shared__ __align__(16) __bf16 Bs[128 * 64];

    const int t = threadIdx.x;
    const int w = t >> 6, lane = t & 63, l16 = lane & 15, q = lane >> 4;
    const int wm = w >> 1, wn = w & 1;

    const int ar = t >> 4;           // A: row-within-pass 0..15
    const int ak = (t & 15) * 4;     // A: float4 column
    const int br = lane >> 3;        // B: row-within-8
    const int bg = (lane & 7) * 8;   // B: 8-elem granule

    f32x4 acc[4][4] = {};

    for (int ks = 0; ks < 8; ++ks) {
        const int k0 = ks * 64;
        __syncthreads();
        // ---- B tile via async global->LDS (no VGPR roundtrip, no cvt) ----
        #pragma unroll
        for (int pb = 0; pb < 4; ++pb) {
            const int rbase = pb * 32 + w * 8;   // wave-uniform
            gload_lds16(&XTb[(size_t)(n0 + rbase + br) * C_ + k0 + bg],
                        &Bs[rbase * 64]);
        }
        // ---- A tile (weights fp32 -> bf16) ----
        #pragma unroll
        for (int pa = 0; pa < 8; ++pa) {
            const int row = pa * 16 + ar;
            const float4 f = *(const float4*)&W[(size_t)(m0 + row) * C_ + k0 + ak];
            bf16x4 v;
            v[0] = (__bf16)f.x; v[1] = (__bf16)f.y;
            v[2] = (__bf16)f.z; v[3] = (__bf16)f.w;
            *(bf16x4*)&As[row * 64 + ak] = v;
        }
        __syncthreads();   // drains vmcnt (global_load_lds) + lgkm
        // ---- MFMA ----
        #pragma unroll
        for (int kk = 0; kk < 2; ++kk) {
            bf16x8 af[4], bfr[4];
            #pragma unroll
            for (int mi = 0; mi < 4; ++mi)
                af[mi] = *(bf16x8*)&As[(wm * 64 + mi * 16 + l16) * 64 + kk * 32 + q * 8];
            #pragma unroll
            for (int ni = 0; ni < 4; ++ni)
                bfr[ni] = *(bf16x8*)&Bs[(wn * 64 + ni * 16 + l16) * 64 + kk * 32 + q * 8];
            #pragma unroll
            for (int mi = 0; mi < 4; ++mi)
                #pragma unroll
                for (int ni = 0; ni < 4; ++ni)
                    acc[mi][ni] = MFMA16(af[mi], bfr[ni], acc[mi][ni]);
        }
    }

    #pragma unroll
    for (int mi = 0; mi < 4; ++mi) {
        #pragma unroll
        for (int r = 0; r < 4; ++r) {
            const int m = m0 + wm * 64 + mi * 16 + q * 4 + r;
            const float bv_ = bias[m];
            #pragma unroll
            for (int ni = 0; ni < 4; ++ni) {
                const int n = n0 + wn * 64 + ni * 16 + l16;
                Yb[(size_t)m * HW_ + n] = (__bf16)(acc[mi][ni][r] + bv_);
            }
        }
    }
}

// ---------------------------------------------------------------------------
// Scores partial (split-K): S_partial[kc][bn][64][64] = Q-chunk . K-chunk^T.
// Grid (128 bn, 6 kc); each block does 6 of the 36 K-iters. No softmax here.
// ---------------------------------------------------------------------------
__global__ __launch_bounds__(256) void attn_scores_part(
    const __bf16* __restrict__ Qw, const __bf16* __restrict__ Kw,
    float* __restrict__ Sp)
{
    const int bn  = blockIdx.x;
    const int kcs = blockIdx.y;
    const __bf16* Qb = Qw + (size_t)bn * 64 * HW_;
    const __bf16* Kb = Kw + (size_t)bn * 64 * HW_;

    __shared__ __align__(16) __bf16 Qs[64 * 72];
    __shared__ __align__(16) __bf16 Ks[64 * 72];

    const int t    = threadIdx.x;
    const int w    = t >> 6;
    const int lane = t & 63;
    const int l16  = lane & 15;
    const int q    = lane >> 4;
    const int row  = t >> 2;
    const int kc   = (t & 3) * 16;

    f32x4 acc[4] = {};

    for (int it = 0; it < 6; ++it) {
        const int k0 = kcs * 384 + it * 64;
        __syncthreads();
        *(bf16x8*)&Qs[row * 72 + kc]     = *(const bf16x8*)&Qb[(size_t)row * HW_ + k0 + kc];
        *(bf16x8*)&Qs[row * 72 + kc + 8] = *(const bf16x8*)&Qb[(size_t)row * HW_ + k0 + kc + 8];
        *(bf16x8*)&Ks[row * 72 + kc]     = *(const bf16x8*)&Kb[(size_t)row * HW_ + k0 + kc];
        *(bf16x8*)&Ks[row * 72 + kc + 8] = *(const bf16x8*)&Kb[(size_t)row * HW_ + k0 + kc + 8];
        __syncthreads();
        #pragma unroll
        for (int kk = 0; kk < 2; ++kk) {
            const bf16x8 a = *(bf16x8*)&Qs[(w * 16 + l16) * 72 + kk * 32 + q * 8];
            #pragma unroll
            for (int ni = 0; ni < 4; ++ni) {
                const bf16x8 bb = *(bf16x8*)&Ks[(ni * 16 + l16) * 72 + kk * 32 + q * 8];
                acc[ni] = MFMA16(a, bb, acc[ni]);
            }
        }
    }

    float* S = Sp + ((size_t)kcs * 128 + bn) * 4096;
    #pragma unroll
    for (int r = 0; r < 4; ++r)
        #pragma unroll
        for (int ni = 0; ni < 4; ++ni)
            S[(w * 16 + q * 4 + r) * 64 + ni * 16 + l16] = acc[ni][r];
}

// ---------------------------------------------------------------------------
// Softmax reduce: sum 6 partials, scale, softmax per row, write P bf16.
// Grid 128; thread t: row = t>>2, col chunk = (t&3)*16. Row reductions via
// __shfl_xor over the 4 lanes sharing a row.
// ---------------------------------------------------------------------------
__global__ __launch_bounds__(256) void softmax_reduce(
    const float* __restrict__ Sp, __bf16* __restrict__ Pw)
{
    const int bn = blockIdx.x;
    const int t  = threadIdx.x;
    const int r  = t >> 2;
    const int c0 = (t & 3) * 16;

    float v[16];
    #pragma unroll
    for (int j = 0; j < 16; ++j) v[j] = 0.f;
    #pragma unroll
    for (int kc = 0; kc < 6; ++kc) {
        const float* s = Sp + ((size_t)kc * 128 + bn) * 4096 + r * 64 + c0;
        #pragma unroll
        for (int j4 = 0; j4 < 4; ++j4) {
            const float4 f = *(const float4*)&s[j4 * 4];
            v[j4 * 4 + 0] += f.x; v[j4 * 4 + 1] += f.y;
            v[j4 * 4 + 2] += f.z; v[j4 * 4 + 3] += f.w;
        }
    }
    float mx = -1e30f;
    #pragma unroll
    for (int j = 0; j < 16; ++j) { v[j] *= SCALE_; mx = fmaxf(mx, v[j]); }
    mx = fmaxf(mx, __shfl_xor(mx, 1));
    mx = fmaxf(mx, __shfl_xor(mx, 2));
    float s = 0.f;
    #pragma unroll
    for (int j = 0; j < 16; ++j) { v[j] = __expf(v[j] - mx); s += v[j]; }
    s += __shfl_xor(s, 1);
    s += __shfl_xor(s, 2);
    const float inv = 1.f / s;
    bf16x8 o0, o1;
    #pragma unroll
    for (int j = 0; j < 8; ++j) {
        o0[j] = (__bf16)(v[j] * inv);
        o1[j] = (__bf16)(v[8 + j] * inv);
    }
    *(bf16x8*)&Pw[(size_t)bn * 4096 + r * 64 + c0]     = o0;
    *(bf16x8*)&Pw[(size_t)bn * 4096 + r * 64 + c0 + 8] = o1;
}

// ---------------------------------------------------------------------------
// O = P @ V, output TRANSPOSED: AOT[b][hw][c] bf16 (so proj_out is a clean
// B^T GEMM). Grid (9 d-slabs, 128 bn). V transposed per-wave in LDS
// (quad-packed, aligned b128 stores).
// ---------------------------------------------------------------------------
__global__ __launch_bounds__(256) void attn_pv(
    const __bf16* __restrict__ Pw, const __bf16* __restrict__ Vw,
    __bf16* __restrict__ AOT)
{
    const int dsl = blockIdx.x;
    const int bn  = blockIdx.y;
    const int t    = threadIdx.x;
    const int w    = t >> 6;
    const int lane = t & 63;
    const int l16  = lane & 15;
    const int q    = lane >> 4;

    __shared__ __align__(16) __bf16 Ps[64 * 72];
    __shared__ __align__(16) __bf16 Vt[4][16 * 264];

    {
        const int row = t >> 2;
        const int kc  = (t & 3) * 16;
        *(bf16x8*)&Ps[row * 72 + kc]     = *(const bf16x8*)&Pw[(size_t)bn * 4096 + row * 64 + kc];
        *(bf16x8*)&Ps[row * 72 + kc + 8] = *(const bf16x8*)&Pw[(size_t)bn * 4096 + row * 64 + kc + 8];
    }

    const __bf16* Vb = Vw + (size_t)bn * 64 * HW_;
    const int d0w = dsl * 256 + w * 64;
    {
        const int m4 = lane & 15;
        const int kh = (lane >> 4) * 16;
        __bf16 rr[4][16];
        #pragma unroll
        for (int j = 0; j < 16; ++j) {
            const bf16x4 v = *(const bf16x4*)&Vb[(size_t)(kh + j) * HW_ + d0w + 4 * m4];
            #pragma unroll
            for (int e = 0; e < 4; ++e) rr[e][j] = v[e];
        }
        #pragma unroll
        for (int e = 0; e < 4; ++e) {
            bf16x8 s0, s1;
            #pragma unroll
            for (int j = 0; j < 8; ++j) { s0[j] = rr[e][j]; s1[j] = rr[e][8 + j]; }
            *(bf16x8*)&Vt[w][m4 * 264 + e * 64 + kh]     = s0;
            *(bf16x8*)&Vt[w][m4 * 264 + e * 64 + kh + 8] = s1;
        }
    }
    __syncthreads();

    f32x4 acc[4][4] = {};
    #pragma unroll
    for (int kk = 0; kk < 2; ++kk) {
        bf16x8 af[4], bfr[4];
        #pragma unroll
        for (int mi = 0; mi < 4; ++mi)
            af[mi] = *(bf16x8*)&Ps[(mi * 16 + l16) * 72 + kk * 32 + q * 8];
        #pragma unroll
        for (int ni = 0; ni < 4; ++ni) {
            const int dl = ni * 16 + l16;
            bfr[ni] = *(bf16x8*)&Vt[w][(dl >> 2) * 264 + (dl & 3) * 64 + kk * 32 + q * 8];
        }
        #pragma unroll
        for (int mi = 0; mi < 4; ++mi)
            #pragma unroll
            for (int ni = 0; ni < 4; ++ni)
                acc[mi][ni] = MFMA16(af[mi], bfr[ni], acc[mi][ni]);
    }

    // write AOT[b][hw=d][c = nh*64 + m], 4 consecutive m per lane -> bf16x4
    const int bb = bn >> 3;
    const int nh = bn & 7;
    #pragma unroll
    for (int mi = 0; mi < 4; ++mi)
        #pragma unroll
        for (int ni = 0; ni < 4; ++ni) {
            const int d = d0w + ni * 16 + l16;
            bf16x4 o;
            #pragma unroll
            for (int r = 0; r < 4; ++r) o[r] = (__bf16)acc[mi][ni][r];
            *(bf16x4*)&AOT[((size_t)bb * HW_ + d) * C_ + nh * 64 + mi * 16 + q * 4] = o;
        }
}

// ---------------------------------------------------------------------------
// Output projection: out[b][o][hw] = sum_c Wo[o][c] * AOT[b][hw][c] + bo[o].
// Same m97 GEMM structure, fp32 output.
// ---------------------------------------------------------------------------
__global__ __launch_bounds__(256) void proj_out(
    const __bf16* __restrict__ AOT, const float* __restrict__ W,
    const float* __restrict__ bias, float* __restrict__ out)
{
    const int b  = blockIdx.z;
    const int n0 = blockIdx.x * 128;
    const int m0 = blockIdx.y * 128;
    const __bf16* XTb = AOT + (size_t)b * HW_ * C_;
    float* Yb = out + (size_t)b * C_ * HW_;

    __shared__ __align__(16) __bf16 As[128 * 64];
    __shared__ __align__(16) __bf16 Bs[128 * 64];

    const int t = threadIdx.x;
    const int w = t >> 6, lane = t & 63, l16 = lane & 15, q = lane >> 4;
    const int wm = w >> 1, wn = w & 1;

    const int ar = t >> 4;
    const int ak = (t & 15) * 4;
    const int br = lane >> 3;
    const int bg = (lane & 7) * 8;

    f32x4 acc[4][4] = {};

    for (int ks = 0; ks < 8; ++ks) {
        const int k0 = ks * 64;
        __syncthreads();
        #pragma unroll
        for (int pb = 0; pb < 4; ++pb) {
            const int rbase = pb * 32 + w * 8;
            gload_lds16(&XTb[(size_t)(n0 + rbase + br) * C_ + k0 + bg],
                        &Bs[rbase * 64]);
        }
        #pragma unroll
        for (int pa = 0; pa < 8; ++pa) {
            const int row = pa * 16 + ar;
            const float4 f = *(const float4*)&W[(size_t)(m0 + row) * C_ + k0 + ak];
            bf16x4 v;
            v[0] = (__bf16)f.x; v[1] = (__bf16)f.y;
            v[2] = (__bf16)f.z; v[3] = (__bf16)f.w;
            *(bf16x4*)&As[row * 64 + ak] = v;
        }
        __syncthreads();
        #pragma unroll
        for (int kk = 0; kk < 2; ++kk) {
            bf16x8 af[4], bfr[4];
            #pragma unroll
            for (int mi = 0; mi < 4; ++mi)
                af[mi] = *(bf16x8*)&As[(wm * 64 + mi * 16 + l16) * 64 + kk * 32 + q * 8];
            #pragma unroll
            for (int ni = 0; ni < 4; ++ni)
                bfr[ni] = *(bf16x8*)&Bs[(wn * 64 + ni * 16 + l16) * 64 + kk * 32 + q * 8];
            #pragma unroll
            for (int mi = 0; mi < 4; ++mi)
                #pragma unroll
                for (int ni = 0; ni < 4; ++ni)
                    acc[mi][ni] = MFMA16(af[mi], bfr[ni], acc[mi][ni]);
        }
    }

    #pragma unroll
    for (int mi = 0; mi < 4; ++mi) {
        #pragma unroll
        for (int r = 0; r < 4; ++r) {
            const int m = m0 + wm * 64 + mi * 16 + q * 4 + r;
            const float bv_ = bias[m];
            #pragma unroll
            for (int ni = 0; ni < 4; ++ni) {
                const int n = n0 + wn * 64 + ni * 16 + l16;
                Yb[(size_t)m * HW_ + n] = acc[mi][ni][r] + bv_;
            }
        }
    }
}

// ---------------------------------------------------------------------------
extern "C" void kernel_launch(void* const* d_in, const int* in_sizes, int n_in,
                              void* d_out, int out_size, void* d_ws, size_t ws_size,
                              hipStream_t stream)
{
    (void)in_sizes; (void)n_in; (void)out_size; (void)ws_size;
    const float* qf = (const float*)d_in[0];
    const float* kf = (const float*)d_in[1];
    const float* vf = (const float*)d_in[2];
    const float* Wq = (const float*)d_in[3];
    const float* bq = (const float*)d_in[4];
    const float* Wk = (const float*)d_in[5];
    const float* bk = (const float*)d_in[6];
    const float* Wv = (const float*)d_in[7];
    const float* bv = (const float*)d_in[8];
    const float* Wo = (const float*)d_in[9];
    const float* bo = (const float*)d_in[10];

    const size_t QE = (size_t)B_ * C_ * HW_;   // 18,874,368 elems
    // region0 (37.75 MB) serves XT -> Sp -> AOT sequentially (all hazards are
    // stream-serial). Total ws = 4*QE*2 + 1 MB = 152,043,520 B (same as R1).
    __bf16* region0 = (__bf16*)d_ws;
    __bf16* XT  = region0;
    float*  Sp  = (float*)region0;             // 6*128*4096*4 = 12.6 MB
    __bf16* AOT = region0;
    __bf16* Qw  = region0 + QE;
    __bf16* Kw  = Qw + QE;
    __bf16* Vw  = Kw + QE;
    __bf16* Pw  = Vw + QE;                     // 128*64*64 bf16 = 1 MB

    // per-p: transpose then GEMM (XT buffer reused across p)
    transpose_cvt<<<dim3(18, 8, 16), 256, 0, stream>>>(qf, XT);
    proj_gemm    <<<dim3(18, 4, 16), 256, 0, stream>>>(XT, Wq, bq, Qw);
    transpose_cvt<<<dim3(18, 8, 16), 256, 0, stream>>>(kf, XT);
    proj_gemm    <<<dim3(18, 4, 16), 256, 0, stream>>>(XT, Wk, bk, Kw);
    transpose_cvt<<<dim3(18, 8, 16), 256, 0, stream>>>(vf, XT);
    proj_gemm    <<<dim3(18, 4, 16), 256, 0, stream>>>(XT, Wv, bv, Vw);

    attn_scores_part<<<dim3(128, 6), 256, 0, stream>>>(Qw, Kw, Sp);
    softmax_reduce  <<<dim3(128),    256, 0, stream>>>(Sp, Pw);
    attn_pv         <<<dim3(9, 128), 256, 0, stream>>>(Pw, Vw, AOT);
    proj_out        <<<dim3(18, 4, 16), 256, 0, stream>>>(AOT, Wo, bo, (float*)d_out);
}

// Round 3
// 424.816 us; speedup vs baseline: 1.1521x; 1.1497x over previous
//
#include <hip/hip_runtime.h>
#include <hip/hip_bf16.h>

// Problem constants
#define B_   16
#define C_   512
#define HW_  2304
#define NH_  8
#define HD_  64
#define SCALE_ 0.125f

typedef __bf16 bf16x8 __attribute__((ext_vector_type(8)));
typedef __bf16 bf16x4 __attribute__((ext_vector_type(4)));
typedef float  f32x4  __attribute__((ext_vector_type(4)));

#define MFMA16(a, b, c) __builtin_amdgcn_mfma_f32_16x16x32_bf16((a), (b), (c), 0, 0, 0)

// async global->LDS, 16B/lane; LDS dest = wave-uniform base + lane*16
__device__ __forceinline__ void gload_lds16(const void* g, void* l) {
    __builtin_amdgcn_global_load_lds(
        (const __attribute__((address_space(1))) unsigned int*)g,
        (__attribute__((address_space(3))) unsigned int*)l, 16, 0, 0);
}

// ---------------------------------------------------------------------------
// prep: (z<16)  transpose+convert X[b][c][hw] fp32 -> XT[b][hw][c] bf16
//       (z==16) convert W fp32 -> Wb bf16 (128 of the 144 xy-blocks)
// ---------------------------------------------------------------------------
__global__ __launch_bounds__(256) void prep(
    const float* __restrict__ X, __bf16* __restrict__ XT,
    const float* __restrict__ W, __bf16* __restrict__ Wb)
{
    const int t = threadIdx.x;
    if (blockIdx.z == 16) {
        const int bid = blockIdx.y * 18 + blockIdx.x;
        if (bid < 128) {
            const int idx = bid * 2048 + t * 8;
            const float4 f0 = *(const float4*)&W[idx];
            const float4 f1 = *(const float4*)&W[idx + 4];
            bf16x8 o;
            o[0] = (__bf16)f0.x; o[1] = (__bf16)f0.y; o[2] = (__bf16)f0.z; o[3] = (__bf16)f0.w;
            o[4] = (__bf16)f1.x; o[5] = (__bf16)f1.y; o[6] = (__bf16)f1.z; o[7] = (__bf16)f1.w;
            *(bf16x8*)&Wb[idx] = o;
        }
        return;
    }
    const int b  = blockIdx.z;
    const int c0 = blockIdx.y * 64;
    const int h0 = blockIdx.x * 128;
    const float* Xb = X + (size_t)b * C_ * HW_;
    __bf16* XTb = XT + (size_t)b * HW_ * C_;

    __shared__ float Ts[64 * 129];

    #pragma unroll
    for (int p = 0; p < 8; ++p) {
        const int c  = p * 8 + (t >> 5);
        const int hg = (t & 31) * 4;
        const float4 v = *(const float4*)&Xb[(size_t)(c0 + c) * HW_ + h0 + hg];
        Ts[c * 129 + hg + 0] = v.x;
        Ts[c * 129 + hg + 1] = v.y;
        Ts[c * 129 + hg + 2] = v.z;
        Ts[c * 129 + hg + 3] = v.w;
    }
    __syncthreads();
    #pragma unroll
    for (int p = 0; p < 4; ++p) {
        const int hw = p * 32 + (t >> 3);
        const int g  = (t & 7) * 8;
        bf16x8 o;
        #pragma unroll
        for (int e = 0; e < 8; ++e)
            o[e] = (__bf16)Ts[(g + e) * 129 + hw];
        *(bf16x8*)&XTb[(size_t)(h0 + hw) * C_ + c0 + g] = o;
    }
}

// ---------------------------------------------------------------------------
// GEMM core: Y[b][o][hw] = sum_c Wb[o][c] * XT[b][hw][c] (+bias).
// 128x128 tile, BK=64, 4 waves. BOTH operands via global_load_lds dwordx4
// with XOR granule swizzle: lane loads source granule (lane&7)^(lane>>3);
// fragment reads at granule (kk*4+q)^(l16&7) -> 2 lanes/bank (free, m136).
// ---------------------------------------------------------------------------
template <typename OUT_T>
__device__ __forceinline__ void gemm_body(
    const __bf16* __restrict__ XTb, const __bf16* __restrict__ Wb,
    const float* __restrict__ bias, OUT_T* __restrict__ Yb,
    int n0, int m0)
{
    __shared__ __align__(16) __bf16 As[128 * 64];
    __shared__ __align__(16) __bf16 Bs[128 * 64];

    const int t = threadIdx.x;
    const int w = t >> 6, lane = t & 63, l16 = lane & 15, q = lane >> 4;
    const int wm = w >> 1, wn = w & 1;
    const int sr = lane >> 3;                    // row within 8
    const int sg = ((lane & 7) ^ (lane >> 3)) * 8; // swizzled source granule

    f32x4 acc[4][4] = {};

    for (int ks = 0; ks < 8; ++ks) {
        const int k0 = ks * 64;
        __syncthreads();
        #pragma unroll
        for (int p = 0; p < 4; ++p) {
            const int rb = p * 32 + w * 8;       // wave-uniform
            gload_lds16(&Wb [(size_t)(m0 + rb + sr) * C_ + k0 + sg], &As[rb * 64]);
            gload_lds16(&XTb[(size_t)(n0 + rb + sr) * C_ + k0 + sg], &Bs[rb * 64]);
        }
        __syncthreads();
        #pragma unroll
        for (int kk = 0; kk < 2; ++kk) {
            const int sw = ((kk * 4 + q) ^ (l16 & 7)) * 8;
            bf16x8 af[4], bfr[4];
            #pragma unroll
            for (int mi = 0; mi < 4; ++mi)
                af[mi] = *(bf16x8*)&As[(wm * 64 + mi * 16 + l16) * 64 + sw];
            #pragma unroll
            for (int ni = 0; ni < 4; ++ni)
                bfr[ni] = *(bf16x8*)&Bs[(wn * 64 + ni * 16 + l16) * 64 + sw];
            #pragma unroll
            for (int mi = 0; mi < 4; ++mi)
                #pragma unroll
                for (int ni = 0; ni < 4; ++ni)
                    acc[mi][ni] = MFMA16(af[mi], bfr[ni], acc[mi][ni]);
        }
    }

    #pragma unroll
    for (int mi = 0; mi < 4; ++mi) {
        #pragma unroll
        for (int r = 0; r < 4; ++r) {
            const int m = m0 + wm * 64 + mi * 16 + q * 4 + r;
            const float bv_ = bias[m];
            #pragma unroll
            for (int ni = 0; ni < 4; ++ni) {
                const int n = n0 + wn * 64 + ni * 16 + l16;
                Yb[(size_t)m * HW_ + n] = (OUT_T)(acc[mi][ni][r] + bv_);
            }
        }
    }
}

__global__ __launch_bounds__(256) void proj_gemm(
    const __bf16* __restrict__ XT, const __bf16* __restrict__ Wb,
    const float* __restrict__ bias, __bf16* __restrict__ Y)
{
    const int b = blockIdx.z;
    gemm_body<__bf16>(XT + (size_t)b * HW_ * C_, Wb, bias,
                      Y + (size_t)b * C_ * HW_, blockIdx.x * 128, blockIdx.y * 128);
}

__global__ __launch_bounds__(256) void proj_out(
    const __bf16* __restrict__ AOT, const __bf16* __restrict__ Wb,
    const float* __restrict__ bias, float* __restrict__ out)
{
    const int b = blockIdx.z;
    gemm_body<float>(AOT + (size_t)b * HW_ * C_, Wb, bias,
                     out + (size_t)b * C_ * HW_, blockIdx.x * 128, blockIdx.y * 128);
}

// ---------------------------------------------------------------------------
// Scores partial (split-K 4): S_partial[kc][bn][64][64], K-chunk = 576.
// Q/K tiles 64x64 via swizzled global_load_lds. Wave w owns rows w*16..+15.
// ---------------------------------------------------------------------------
__global__ __launch_bounds__(256) void attn_scores_part(
    const __bf16* __restrict__ Qw, const __bf16* __restrict__ Kw,
    float* __restrict__ Sp)
{
    const int bn  = blockIdx.x;
    const int kcs = blockIdx.y;
    const __bf16* Qb = Qw + (size_t)bn * 64 * HW_;
    const __bf16* Kb = Kw + (size_t)bn * 64 * HW_;

    __shared__ __align__(16) __bf16 Qs[64 * 64];
    __shared__ __align__(16) __bf16 Ks[64 * 64];

    const int t    = threadIdx.x;
    const int w    = t >> 6;
    const int lane = t & 63;
    const int l16  = lane & 15;
    const int q    = lane >> 4;
    const int sr   = lane >> 3;
    const int sg   = ((lane & 7) ^ (lane >> 3)) * 8;

    f32x4 acc[4] = {};

    for (int it = 0; it < 9; ++it) {
        const int k0 = kcs * 576 + it * 64;
        __syncthreads();
        #pragma unroll
        for (int p = 0; p < 2; ++p) {
            const int rb = w * 16 + p * 8;       // wave-uniform, rows w*16..+15
            gload_lds16(&Qb[(size_t)(rb + sr) * HW_ + k0 + sg], &Qs[rb * 64]);
            gload_lds16(&Kb[(size_t)(rb + sr) * HW_ + k0 + sg], &Ks[rb * 64]);
        }
        __syncthreads();
        #pragma unroll
        for (int kk = 0; kk < 2; ++kk) {
            const int sw = ((kk * 4 + q) ^ (l16 & 7)) * 8;
            const bf16x8 a = *(bf16x8*)&Qs[(w * 16 + l16) * 64 + sw];
            #pragma unroll
            for (int ni = 0; ni < 4; ++ni) {
                const bf16x8 bb = *(bf16x8*)&Ks[(ni * 16 + l16) * 64 + sw];
                acc[ni] = MFMA16(a, bb, acc[ni]);
            }
        }
    }

    float* S = Sp + ((size_t)kcs * 128 + bn) * 4096;
    #pragma unroll
    for (int r = 0; r < 4; ++r)
        #pragma unroll
        for (int ni = 0; ni < 4; ++ni)
            S[(w * 16 + q * 4 + r) * 64 + ni * 16 + l16] = acc[ni][r];
}

// ---------------------------------------------------------------------------
// Softmax reduce: sum 4 partials, scale, softmax/row, write P bf16.
// ---------------------------------------------------------------------------
__global__ __launch_bounds__(256) void softmax_reduce(
    const float* __restrict__ Sp, __bf16* __restrict__ Pw)
{
    const int bn = blockIdx.x;
    const int t  = threadIdx.x;
    const int r  = t >> 2;
    const int c0 = (t & 3) * 16;

    float v[16];
    #pragma unroll
    for (int j = 0; j < 16; ++j) v[j] = 0.f;
    #pragma unroll
    for (int kc = 0; kc < 4; ++kc) {
        const float* s = Sp + ((size_t)kc * 128 + bn) * 4096 + r * 64 + c0;
        #pragma unroll
        for (int j4 = 0; j4 < 4; ++j4) {
            const float4 f = *(const float4*)&s[j4 * 4];
            v[j4 * 4 + 0] += f.x; v[j4 * 4 + 1] += f.y;
            v[j4 * 4 + 2] += f.z; v[j4 * 4 + 3] += f.w;
        }
    }
    float mx = -1e30f;
    #pragma unroll
    for (int j = 0; j < 16; ++j) { v[j] *= SCALE_; mx = fmaxf(mx, v[j]); }
    mx = fmaxf(mx, __shfl_xor(mx, 1));
    mx = fmaxf(mx, __shfl_xor(mx, 2));
    float s = 0.f;
    #pragma unroll
    for (int j = 0; j < 16; ++j) { v[j] = __expf(v[j] - mx); s += v[j]; }
    s += __shfl_xor(s, 1);
    s += __shfl_xor(s, 2);
    const float inv = 1.f / s;
    bf16x8 o0, o1;
    #pragma unroll
    for (int j = 0; j < 8; ++j) {
        o0[j] = (__bf16)(v[j] * inv);
        o1[j] = (__bf16)(v[8 + j] * inv);
    }
    *(bf16x8*)&Pw[(size_t)bn * 4096 + r * 64 + c0]     = o0;
    *(bf16x8*)&Pw[(size_t)bn * 4096 + r * 64 + c0 + 8] = o1;
}

// ---------------------------------------------------------------------------
// O = P @ V -> AOT[b][hw][c] bf16.  Grid (10, 128): x<9 = d-slabs, x==9 =
// Wo fp32->bf16 conversion blocks (into dead Qw region).
// ---------------------------------------------------------------------------
__global__ __launch_bounds__(256) void attn_pv(
    const __bf16* __restrict__ Pw, const __bf16* __restrict__ Vw,
    __bf16* __restrict__ AOT, const float* __restrict__ Wo, __bf16* __restrict__ WoB)
{
    const int t = threadIdx.x;
    if (blockIdx.x == 9) {
        const int idx = blockIdx.y * 2048 + t * 8;
        const float4 f0 = *(const float4*)&Wo[idx];
        const float4 f1 = *(const float4*)&Wo[idx + 4];
        bf16x8 o;
        o[0] = (__bf16)f0.x; o[1] = (__bf16)f0.y; o[2] = (__bf16)f0.z; o[3] = (__bf16)f0.w;
        o[4] = (__bf16)f1.x; o[5] = (__bf16)f1.y; o[6] = (__bf16)f1.z; o[7] = (__bf16)f1.w;
        *(bf16x8*)&WoB[idx] = o;
        return;
    }
    const int dsl = blockIdx.x;
    const int bn  = blockIdx.y;
    const int w    = t >> 6;
    const int lane = t & 63;
    const int l16  = lane & 15;
    const int q    = lane >> 4;

    __shared__ __align__(16) __bf16 Ps[64 * 72];
    __shared__ __align__(16) __bf16 Vt[4][16 * 264];

    {
        const int row = t >> 2;
        const int kc  = (t & 3) * 16;
        *(bf16x8*)&Ps[row * 72 + kc]     = *(const bf16x8*)&Pw[(size_t)bn * 4096 + row * 64 + kc];
        *(bf16x8*)&Ps[row * 72 + kc + 8] = *(const bf16x8*)&Pw[(size_t)bn * 4096 + row * 64 + kc + 8];
    }

    const __bf16* Vb = Vw + (size_t)bn * 64 * HW_;
    const int d0w = dsl * 256 + w * 64;
    {
        const int m4 = lane & 15;
        const int kh = (lane >> 4) * 16;
        __bf16 rr[4][16];
        #pragma unroll
        for (int j = 0; j < 16; ++j) {
            const bf16x4 v = *(const bf16x4*)&Vb[(size_t)(kh + j) * HW_ + d0w + 4 * m4];
            #pragma unroll
            for (int e = 0; e < 4; ++e) rr[e][j] = v[e];
        }
        #pragma unroll
        for (int e = 0; e < 4; ++e) {
            bf16x8 s0, s1;
            #pragma unroll
            for (int j = 0; j < 8; ++j) { s0[j] = rr[e][j]; s1[j] = rr[e][8 + j]; }
            *(bf16x8*)&Vt[w][m4 * 264 + e * 64 + kh]     = s0;
            *(bf16x8*)&Vt[w][m4 * 264 + e * 64 + kh + 8] = s1;
        }
    }
    __syncthreads();

    f32x4 acc[4][4] = {};
    #pragma unroll
    for (int kk = 0; kk < 2; ++kk) {
        bf16x8 af[4], bfr[4];
        #pragma unroll
        for (int mi = 0; mi < 4; ++mi)
            af[mi] = *(bf16x8*)&Ps[(mi * 16 + l16) * 72 + kk * 32 + q * 8];
        #pragma unroll
        for (int ni = 0; ni < 4; ++ni) {
            const int dl = ni * 16 + l16;
            bfr[ni] = *(bf16x8*)&Vt[w][(dl >> 2) * 264 + (dl & 3) * 64 + kk * 32 + q * 8];
        }
        #pragma unroll
        for (int mi = 0; mi < 4; ++mi)
            #pragma unroll
            for (int ni = 0; ni < 4; ++ni)
                acc[mi][ni] = MFMA16(af[mi], bfr[ni], acc[mi][ni]);
    }

    const int bb = bn >> 3;
    const int nh = bn & 7;
    #pragma unroll
    for (int mi = 0; mi < 4; ++mi)
        #pragma unroll
        for (int ni = 0; ni < 4; ++ni) {
            const int d = d0w + ni * 16 + l16;
            bf16x4 o;
            #pragma unroll
            for (int r = 0; r < 4; ++r) o[r] = (__bf16)acc[mi][ni][r];
            *(bf16x4*)&AOT[((size_t)bb * HW_ + d) * C_ + nh * 64 + mi * 16 + q * 4] = o;
        }
}

// ---------------------------------------------------------------------------
extern "C" void kernel_launch(void* const* d_in, const int* in_sizes, int n_in,
                              void* d_out, int out_size, void* d_ws, size_t ws_size,
                              hipStream_t stream)
{
    (void)in_sizes; (void)n_in; (void)out_size; (void)ws_size;
    const float* qf = (const float*)d_in[0];
    const float* kf = (const float*)d_in[1];
    const float* vf = (const float*)d_in[2];
    const float* Wq = (const float*)d_in[3];
    const float* bq = (const float*)d_in[4];
    const float* Wk = (const float*)d_in[5];
    const float* bk = (const float*)d_in[6];
    const float* Wv = (const float*)d_in[7];
    const float* bv = (const float*)d_in[8];
    const float* Wo = (const float*)d_in[9];
    const float* bo = (const float*)d_in[10];

    const size_t QE = (size_t)B_ * C_ * HW_;   // 18,874,368 elems
    // region0 (37.75 MB): XT -> Sp(8.4MB) -> AOT, all stream-serial.
    // slotP (1 MB): Wb (per-projection) -> Pw.  WoB aliases dead Qw.
    // Total ws = 4*QE*2 + 1 MB = 152,043,520 B (same as prior rounds).
    __bf16* region0 = (__bf16*)d_ws;
    __bf16* XT  = region0;
    float*  Sp  = (float*)region0;             // 4*128*4096*4 = 8.4 MB
    __bf16* AOT = region0;
    __bf16* Qw  = region0 + QE;
    __bf16* Kw  = Qw + QE;
    __bf16* Vw  = Kw + QE;
    __bf16* slotP = Vw + QE;                   // 1 MB
    __bf16* Wb  = slotP;                       // 0.5 MB, dead before Pw written
    __bf16* Pw  = slotP;
    __bf16* WoB = Qw;                          // Qw dead after attn_scores_part

    prep     <<<dim3(18, 8, 17), 256, 0, stream>>>(qf, XT, Wq, Wb);
    proj_gemm<<<dim3(18, 4, 16), 256, 0, stream>>>(XT, Wb, bq, Qw);
    prep     <<<dim3(18, 8, 17), 256, 0, stream>>>(kf, XT, Wk, Wb);
    proj_gemm<<<dim3(18, 4, 16), 256, 0, stream>>>(XT, Wb, bk, Kw);
    prep     <<<dim3(18, 8, 17), 256, 0, stream>>>(vf, XT, Wv, Wb);
    proj_gemm<<<dim3(18, 4, 16), 256, 0, stream>>>(XT, Wb, bv, Vw);

    attn_scores_part<<<dim3(128, 4), 256, 0, stream>>>(Qw, Kw, Sp);
    softmax_reduce  <<<dim3(128),    256, 0, stream>>>(Sp, Pw);
    attn_pv         <<<dim3(10, 128), 256, 0, stream>>>(Pw, Vw, AOT, Wo, WoB);
    proj_out        <<<dim3(18, 4, 16), 256, 0, stream>>>(AOT, WoB, bo, (float*)d_out);
}